// Round 7
// baseline (1395.153 us; speedup 1.0000x reference)
//
#include <hip/hip_runtime.h>
#include <hip/hip_bf16.h>
#include <math.h>

// TokenMoE: x[4,2048,1024] fp32, 8 experts, top-2, D_FF=4096, exact-erf GELU.
// R5: + prefetch double-buffer (T3-min), slot-store+combine (no atomics),
//     XCD-chunked work remap for L2 B-panel reuse. ws ~272 MB (slot aliases w1_bf).

#define D_MODEL 1024
#define N_EXPERTS 8
#define D_FF 4096
#define N_TOKENS 8192

typedef __attribute__((ext_vector_type(8))) short bf16x8;
typedef __attribute__((ext_vector_type(4))) float f32x4;
typedef __attribute__((ext_vector_type(8))) unsigned short ushort8;

__device__ inline unsigned short f2bf(float f) {
    unsigned int u = __float_as_uint(f);
    unsigned int r = (u + 0x7FFFu + ((u >> 16) & 1u)) >> 16;   // RNE
    return (unsigned short)r;
}

__device__ inline void gload_lds16(const void* g, void* l) {
    __builtin_amdgcn_global_load_lds(
        (const __attribute__((address_space(1))) unsigned int*)g,
        (__attribute__((address_space(3))) unsigned int*)l, 16, 0, 0);
}

// ---------------- fp32 -> bf16 conversion, 3 segments fused (8 elems/thread) -------------
__device__ inline void cvt8(const float* __restrict__ src, unsigned short* __restrict__ dst,
                            int i) {
    const float4* s = reinterpret_cast<const float4*>(src) + (size_t)i * 2;
    float4 a = s[0], b = s[1];
    ushort8 r;
    r[0] = f2bf(a.x); r[1] = f2bf(a.y); r[2] = f2bf(a.z); r[3] = f2bf(a.w);
    r[4] = f2bf(b.x); r[5] = f2bf(b.y); r[6] = f2bf(b.z); r[7] = f2bf(b.w);
    *reinterpret_cast<ushort8*>(dst + (size_t)i * 8) = r;
}

__global__ __launch_bounds__(256) void cvt_all(const float* __restrict__ s0, unsigned short* __restrict__ d0, int n0,
                                               const float* __restrict__ s1, unsigned short* __restrict__ d1, int n1,
                                               const float* __restrict__ s2, unsigned short* __restrict__ d2, int n2) {
    int i = blockIdx.x * blockDim.x + threadIdx.x;
    int stride = gridDim.x * blockDim.x;
    int total = n0 + n1 + n2;
    for (; i < total; i += stride) {
        if (i < n0)            cvt8(s0, d0, i);
        else if (i < n0 + n1)  cvt8(s1, d1, i - n0);
        else                   cvt8(s2, d2, i - n0 - n1);
    }
}

// ---------------- gating: logits, softmax, top-2, fill expert lists ----------------
__global__ __launch_bounds__(256) void gate_kernel(const float* __restrict__ x,
                                                   const float* __restrict__ gw,
                                                   int* __restrict__ counts,
                                                   int* __restrict__ list,
                                                   float* __restrict__ pairw) {
    int wave = threadIdx.x >> 6;
    int lane = threadIdx.x & 63;
    int t = blockIdx.x * 4 + wave;
    if (t >= N_TOKENS) return;

    const float4* xr = reinterpret_cast<const float4*>(x + (size_t)t * D_MODEL);
    float4 xv[4];
#pragma unroll
    for (int i = 0; i < 4; i++) xv[i] = xr[lane + 64 * i];

    float acc[N_EXPERTS];
#pragma unroll
    for (int e = 0; e < N_EXPERTS; e++) {
        const float4* gr = reinterpret_cast<const float4*>(gw + (size_t)e * D_MODEL);
        float s = 0.f;
#pragma unroll
        for (int i = 0; i < 4; i++) {
            float4 g = gr[lane + 64 * i];
            s += xv[i].x * g.x + xv[i].y * g.y + xv[i].z * g.z + xv[i].w * g.w;
        }
        acc[e] = s;
    }
#pragma unroll
    for (int e = 0; e < N_EXPERTS; e++) {
        float s = acc[e];
#pragma unroll
        for (int off = 32; off; off >>= 1) s += __shfl_xor(s, off, 64);
        acc[e] = s;
    }
    if (lane == 0) {
        float m = acc[0];
#pragma unroll
        for (int e = 1; e < N_EXPERTS; e++) m = fmaxf(m, acc[e]);
        float p[N_EXPERTS], sum = 0.f;
#pragma unroll
        for (int e = 0; e < N_EXPERTS; e++) { p[e] = expf(acc[e] - m); sum += p[e]; }
        float inv = 1.f / sum;
#pragma unroll
        for (int e = 0; e < N_EXPERTS; e++) p[e] *= inv;
        int i1 = 0;
#pragma unroll
        for (int e = 1; e < N_EXPERTS; e++) if (p[e] > p[i1]) i1 = e;
        int i2 = (i1 == 0) ? 1 : 0;
#pragma unroll
        for (int e = 0; e < N_EXPERTS; e++) {
            if (e == i1) continue;
            if (p[e] > p[i2]) i2 = e;
        }
        int pos1 = atomicAdd(&counts[i1], 1);
        list[i1 * N_TOKENS + pos1] = t * 2 + 0;
        pairw[i1 * N_TOKENS + pos1] = p[i1];
        int pos2 = atomicAdd(&counts[i2], 1);
        list[i2 * N_TOKENS + pos2] = t * 2 + 1;
        pairw[i2 * N_TOKENS + pos2] = p[i2];
    }
}

// ---------------- grouped GEMM: 128x128 tile, BK=64, 4 waves, prefetch dbuf --------------
// LAYER==1: h[entry] = gelu(x[t] @ w1[e]^T + b1[e])
// LAYER==2: slot[entry] = pairw * (h[entry] @ w2[e]^T + b2[e])   (plain stores)
template <int LAYER>
__global__ __launch_bounds__(256) void moe_gemm(const unsigned short* __restrict__ A_src,
                                                const unsigned short* __restrict__ B_src,
                                                const float* __restrict__ bias,
                                                const int* __restrict__ counts,
                                                const int* __restrict__ list,
                                                const float* __restrict__ pairw,
                                                unsigned short* __restrict__ h_out,
                                                float* __restrict__ slot_out) {
    constexpr int KD = (LAYER == 1) ? D_MODEL : D_FF;   // reduction dim
    constexpr int NO = (LAYER == 1) ? D_FF : D_MODEL;   // output cols
    constexpr int NBLK = NO / 128;                      // 32 or 8 (pow2)
    constexpr int NBSH = (NBLK == 32) ? 5 : 3;
    constexpr int MBLK = 64;                            // covers worst-case cnt=8192
    constexpr long TOTAL = (long)NBLK * MBLK * N_EXPERTS;
    constexpr int NT = KD / 64;

    // XCD-chunked remap: bid&7 = XCD (round-robin dispatch); give each XCD a
    // contiguous work chunk, m-fastest within (e,nb) so one B-panel stays hot in L2.
    long bid = blockIdx.x;
    long work = (bid & 7) * (TOTAL >> 3) + (bid >> 3);
    const int mb = (int)(work & (MBLK - 1));
    const int nb = (int)((work >> 6) & (NBLK - 1));
    const int e  = (int)(work >> (6 + NBSH));

    const int cnt = counts[e];
    const int m0 = mb * 128;
    if (m0 >= cnt) return;
    const int n0 = nb * 128;

    __shared__ __align__(16) unsigned short As[2][128 * 64];
    __shared__ __align__(16) unsigned short Bs[2][128 * 64];

    const int tid = threadIdx.x;
    const int wave = tid >> 6, lane = tid & 63;
    const int lr = lane >> 3;        // row within 8-row staging chunk
    const int lc = (lane & 7) * 8;   // bf16-element offset within row (16B/lane)

    const unsigned short* aptr[4];
    const unsigned short* bptr[4];
#pragma unroll
    for (int i = 0; i < 4; i++) {
        int c = wave * 4 + i;
        int ra = c * 8 + lr;                       // tile row 0..127
        int pos = m0 + ra;
        int cpos = pos < cnt ? pos : (cnt - 1);
        int entry = list[e * N_TOKENS + cpos];
        long arow = (LAYER == 1) ? (long)(entry >> 1) : (long)entry;
        aptr[i] = A_src + arow * KD + lc;
        long brow = (long)e * NO + n0 + ra;
        bptr[i] = B_src + brow * KD + lc;
    }

    f32x4 acc[4][4];
#pragma unroll
    for (int m = 0; m < 4; m++)
#pragma unroll
        for (int n = 0; n < 4; n++) acc[m][n] = f32x4{0.f, 0.f, 0.f, 0.f};

    const int wr = (wave >> 1) * 64, wc = (wave & 1) * 64;
    const int fr = lane & 15;        // fragment row (A) / out-col (B)
    const int fk = (lane >> 4) * 8;  // fragment k offset

    // prologue: stage tile 0 into buf 0
#pragma unroll
    for (int i = 0; i < 4; i++) {
        int c = wave * 4 + i;
        gload_lds16(aptr[i], &As[0][c * 8 * 64]);
        gload_lds16(bptr[i], &Bs[0][c * 8 * 64]);
    }
    __syncthreads();   // drains vmcnt(0): buf0 ready

    int buf = 0;
    for (int t = 0; t < NT; ++t) {
        // issue next tile's loads into the other buffer (overlap with compute below)
        if (t + 1 < NT) {
            int k0 = (t + 1) * 64;
#pragma unroll
            for (int i = 0; i < 4; i++) {
                int c = wave * 4 + i;
                gload_lds16(aptr[i] + k0, &As[buf ^ 1][c * 8 * 64]);
                gload_lds16(bptr[i] + k0, &Bs[buf ^ 1][c * 8 * 64]);
            }
        }
        // compute on current buffer
#pragma unroll
        for (int ks = 0; ks < 64; ks += 32) {
            bf16x8 af[4], bfr[4];
#pragma unroll
            for (int m = 0; m < 4; m++)
                af[m] = *reinterpret_cast<const bf16x8*>(&As[buf][(wr + m * 16 + fr) * 64 + ks + fk]);
#pragma unroll
            for (int n = 0; n < 4; n++)
                bfr[n] = *reinterpret_cast<const bf16x8*>(&Bs[buf][(wc + n * 16 + fr) * 64 + ks + fk]);
#pragma unroll
            for (int m = 0; m < 4; m++)
#pragma unroll
                for (int n = 0; n < 4; n++)
                    acc[m][n] = __builtin_amdgcn_mfma_f32_16x16x32_bf16(af[m], bfr[n], acc[m][n], 0, 0, 0);
        }
        __syncthreads();   // drains vmcnt(0) (next buf staged) + lgkmcnt; one barrier/iter
        buf ^= 1;
    }

    // epilogue: C/D layout col=lane&15, row=(lane>>4)*4+j  [m89/m91]
#pragma unroll
    for (int m = 0; m < 4; m++) {
#pragma unroll
        for (int j = 0; j < 4; j++) {
            int row = wr + m * 16 + ((lane >> 4) << 2) + j;
            int pos = m0 + row;
            if (pos >= cnt) continue;
            int entry = list[e * N_TOKENS + pos];
            if (LAYER == 1) {
                unsigned short* hrow = h_out + (long)entry * D_FF + n0;
#pragma unroll
                for (int n = 0; n < 4; n++) {
                    int col = wc + n * 16 + (lane & 15);
                    float v = acc[m][n][j] + bias[e * NO + n0 + col];
                    v = 0.5f * v * (1.f + erff(v * 0.70710678118654752440f));  // exact GELU
                    hrow[col] = f2bf(v);
                }
            } else {
                float w = pairw[e * N_TOKENS + pos];
                float* srow = slot_out + (long)entry * D_MODEL + n0;
#pragma unroll
                for (int n = 0; n < 4; n++) {
                    int col = wc + n * 16 + (lane & 15);
                    srow[col] = (acc[m][n][j] + bias[e * NO + n0 + col]) * w;  // plain store
                }
            }
        }
    }
}

// ---------------- combine: out[t] = slot[2t] + slot[2t+1] ----------------
__global__ __launch_bounds__(256) void combine_kernel(const float* __restrict__ slot,
                                                      float* __restrict__ out) {
    const long n4 = (long)N_TOKENS * D_MODEL / 4;
    const float4* s = reinterpret_cast<const float4*>(slot);
    float4* o = reinterpret_cast<float4*>(out);
    long i = (long)blockIdx.x * blockDim.x + threadIdx.x;
    long stride = (long)gridDim.x * blockDim.x;
    constexpr int C4 = D_MODEL / 4;  // 256
    for (; i < n4; i += stride) {
        long t = i >> 8;             // / 256
        long c = i & (C4 - 1);
        float4 a = s[(2 * t) * C4 + c];
        float4 b = s[(2 * t + 1) * C4 + c];
        float4 r; r.x = a.x + b.x; r.y = a.y + b.y; r.z = a.z + b.z; r.w = a.w + b.w;
        o[i] = r;
    }
}

extern "C" void kernel_launch(void* const* d_in, const int* in_sizes, int n_in,
                              void* d_out, int out_size, void* d_ws, size_t ws_size,
                              hipStream_t stream) {
    const float* x  = (const float*)d_in[0];
    const float* gw = (const float*)d_in[1];
    const float* w1 = (const float*)d_in[2];
    const float* b1 = (const float*)d_in[3];
    const float* w2 = (const float*)d_in[4];
    const float* b2 = (const float*)d_in[5];
    float* out = (float*)d_out;

    char* ws = (char*)d_ws;
    size_t off = 0;
    auto alloc = [&](size_t bytes) {
        void* p = ws + off;
        off += (bytes + 255) & ~(size_t)255;
        return p;
    };
    unsigned short* x_bf  = (unsigned short*)alloc(sizeof(unsigned short) * N_TOKENS * D_MODEL);
    unsigned short* w1_bf = (unsigned short*)alloc(sizeof(unsigned short) * N_EXPERTS * D_FF * D_MODEL);
    unsigned short* w2_bf = (unsigned short*)alloc(sizeof(unsigned short) * N_EXPERTS * D_MODEL * D_FF);
    unsigned short* h_bf  = (unsigned short*)alloc(sizeof(unsigned short) * (size_t)N_TOKENS * 2 * D_FF);
    int*   list  = (int*)alloc(sizeof(int) * N_EXPERTS * N_TOKENS);
    float* pairw = (float*)alloc(sizeof(float) * N_EXPERTS * N_TOKENS);
    int*   counts = (int*)alloc(sizeof(int) * N_EXPERTS);

    // slot buffer (16384 x 1024 f32 = 64 MB) aliases w1_bf (64 MB, dead after layer-1).
    // Same-stream ordering: cvt writes w1_bf -> gemm1 reads it -> gemm2 writes slot -> combine.
    float* slot = (float*)w1_bf;

    hipMemsetAsync(counts, 0, sizeof(int) * N_EXPERTS, stream);

    cvt_all<<<2048, 256, 0, stream>>>(
        x,  x_bf,  N_TOKENS * D_MODEL / 8,
        w1, w1_bf, N_EXPERTS * D_FF * D_MODEL / 8,
        w2, w2_bf, N_EXPERTS * D_MODEL * D_FF / 8);

    gate_kernel<<<N_TOKENS / 4, 256, 0, stream>>>(x, gw, counts, list, pairw);

    moe_gemm<1><<<(D_FF / 128) * 64 * N_EXPERTS, 256, 0, stream>>>(
        x_bf, w1_bf, b1, counts, list, pairw, h_bf, nullptr);
    moe_gemm<2><<<(D_MODEL / 128) * 64 * N_EXPERTS, 256, 0, stream>>>(
        h_bf, w2_bf, b2, counts, list, pairw, nullptr, slot);

    combine_kernel<<<2048, 256, 0, stream>>>(slot, out);
}

// Round 9
// 1349.204 us; speedup vs baseline: 1.0341x; 1.0341x over previous
//
#include <hip/hip_runtime.h>
#include <hip/hip_bf16.h>
#include <math.h>

// TokenMoE: x[4,2048,1024] fp32, 8 experts, top-2, D_FF=4096, exact-erf GELU.
// R7: panel-round-robin XCD remap (balanced across experts, L2 panel reuse kept),
//     prefetch double-buffer, slot-store+combine. ws ~272 MB (slot aliases w1_bf).

#define D_MODEL 1024
#define N_EXPERTS 8
#define D_FF 4096
#define N_TOKENS 8192

typedef __attribute__((ext_vector_type(8))) short bf16x8;
typedef __attribute__((ext_vector_type(4))) float f32x4;
typedef __attribute__((ext_vector_type(8))) unsigned short ushort8;

__device__ inline unsigned short f2bf(float f) {
    unsigned int u = __float_as_uint(f);
    unsigned int r = (u + 0x7FFFu + ((u >> 16) & 1u)) >> 16;   // RNE
    return (unsigned short)r;
}

__device__ inline void gload_lds16(const void* g, void* l) {
    __builtin_amdgcn_global_load_lds(
        (const __attribute__((address_space(1))) unsigned int*)g,
        (__attribute__((address_space(3))) unsigned int*)l, 16, 0, 0);
}

// ---------------- fp32 -> bf16 conversion, 3 segments fused (8 elems/thread) -------------
__device__ inline void cvt8(const float* __restrict__ src, unsigned short* __restrict__ dst,
                            int i) {
    const float4* s = reinterpret_cast<const float4*>(src) + (size_t)i * 2;
    float4 a = s[0], b = s[1];
    ushort8 r;
    r[0] = f2bf(a.x); r[1] = f2bf(a.y); r[2] = f2bf(a.z); r[3] = f2bf(a.w);
    r[4] = f2bf(b.x); r[5] = f2bf(b.y); r[6] = f2bf(b.z); r[7] = f2bf(b.w);
    *reinterpret_cast<ushort8*>(dst + (size_t)i * 8) = r;
}

__global__ __launch_bounds__(256) void cvt_all(const float* __restrict__ s0, unsigned short* __restrict__ d0, int n0,
                                               const float* __restrict__ s1, unsigned short* __restrict__ d1, int n1,
                                               const float* __restrict__ s2, unsigned short* __restrict__ d2, int n2) {
    int i = blockIdx.x * blockDim.x + threadIdx.x;
    int stride = gridDim.x * blockDim.x;
    int total = n0 + n1 + n2;
    for (; i < total; i += stride) {
        if (i < n0)            cvt8(s0, d0, i);
        else if (i < n0 + n1)  cvt8(s1, d1, i - n0);
        else                   cvt8(s2, d2, i - n0 - n1);
    }
}

// ---------------- gating: logits, softmax, top-2, fill expert lists ----------------
__global__ __launch_bounds__(256) void gate_kernel(const float* __restrict__ x,
                                                   const float* __restrict__ gw,
                                                   int* __restrict__ counts,
                                                   int* __restrict__ list,
                                                   float* __restrict__ pairw) {
    int wave = threadIdx.x >> 6;
    int lane = threadIdx.x & 63;
    int t = blockIdx.x * 4 + wave;
    if (t >= N_TOKENS) return;

    const float4* xr = reinterpret_cast<const float4*>(x + (size_t)t * D_MODEL);
    float4 xv[4];
#pragma unroll
    for (int i = 0; i < 4; i++) xv[i] = xr[lane + 64 * i];

    float acc[N_EXPERTS];
#pragma unroll
    for (int e = 0; e < N_EXPERTS; e++) {
        const float4* gr = reinterpret_cast<const float4*>(gw + (size_t)e * D_MODEL);
        float s = 0.f;
#pragma unroll
        for (int i = 0; i < 4; i++) {
            float4 g = gr[lane + 64 * i];
            s += xv[i].x * g.x + xv[i].y * g.y + xv[i].z * g.z + xv[i].w * g.w;
        }
        acc[e] = s;
    }
#pragma unroll
    for (int e = 0; e < N_EXPERTS; e++) {
        float s = acc[e];
#pragma unroll
        for (int off = 32; off; off >>= 1) s += __shfl_xor(s, off, 64);
        acc[e] = s;
    }
    if (lane == 0) {
        float m = acc[0];
#pragma unroll
        for (int e = 1; e < N_EXPERTS; e++) m = fmaxf(m, acc[e]);
        float p[N_EXPERTS], sum = 0.f;
#pragma unroll
        for (int e = 0; e < N_EXPERTS; e++) { p[e] = expf(acc[e] - m); sum += p[e]; }
        float inv = 1.f / sum;
#pragma unroll
        for (int e = 0; e < N_EXPERTS; e++) p[e] *= inv;
        int i1 = 0;
#pragma unroll
        for (int e = 1; e < N_EXPERTS; e++) if (p[e] > p[i1]) i1 = e;
        int i2 = (i1 == 0) ? 1 : 0;
#pragma unroll
        for (int e = 0; e < N_EXPERTS; e++) {
            if (e == i1) continue;
            if (p[e] > p[i2]) i2 = e;
        }
        int pos1 = atomicAdd(&counts[i1], 1);
        list[i1 * N_TOKENS + pos1] = t * 2 + 0;
        pairw[i1 * N_TOKENS + pos1] = p[i1];
        int pos2 = atomicAdd(&counts[i2], 1);
        list[i2 * N_TOKENS + pos2] = t * 2 + 1;
        pairw[i2 * N_TOKENS + pos2] = p[i2];
    }
}

// ---------------- grouped GEMM: 128x128 tile, BK=64, 4 waves, prefetch dbuf --------------
// LAYER==1: h[entry] = gelu(x[t] @ w1[e]^T + b1[e])
// LAYER==2: slot[entry] = pairw * (h[entry] @ w2[e]^T + b2[e])   (plain stores)
template <int LAYER>
__global__ __launch_bounds__(256) void moe_gemm(const unsigned short* __restrict__ A_src,
                                                const unsigned short* __restrict__ B_src,
                                                const float* __restrict__ bias,
                                                const int* __restrict__ counts,
                                                const int* __restrict__ list,
                                                const float* __restrict__ pairw,
                                                unsigned short* __restrict__ h_out,
                                                float* __restrict__ slot_out) {
    constexpr int KD = (LAYER == 1) ? D_MODEL : D_FF;   // reduction dim
    constexpr int NO = (LAYER == 1) ? D_FF : D_MODEL;   // output cols
    constexpr int NBLK = NO / 128;                      // 32 or 8 (pow2)
    constexpr int NBSH = (NBLK == 32) ? 5 : 3;
    constexpr int MBLK = 64;                            // covers worst-case cnt=8192
    constexpr int NT = KD / 64;

    // Panel-round-robin XCD remap: panel p=(e,nb), p%8 == xcd (balanced: each XCD
    // gets NBLK/8 panels of EVERY expert); mb runs contiguously on one XCD so the
    // 128-col B-panel slice stays hot in that XCD's L2.
    long bid = blockIdx.x;
    const int xcd = (int)(bid & 7);
    long seq = bid >> 3;                       // [0, P*MBLK/8)
    const int mb = (int)(seq & (MBLK - 1));    // fastest: same panel for 64 consecutive seq
    const int p  = (int)((seq >> 6) * 8 + xcd);
    const int e  = p >> NBSH;
    const int nb = p & (NBLK - 1);

    const int cnt = counts[e];
    const int m0 = mb * 128;
    if (m0 >= cnt) return;
    const int n0 = nb * 128;

    __shared__ __align__(16) unsigned short As[2][128 * 64];
    __shared__ __align__(16) unsigned short Bs[2][128 * 64];

    const int tid = threadIdx.x;
    const int wave = tid >> 6, lane = tid & 63;
    const int lr = lane >> 3;        // row within 8-row staging chunk
    const int lc = (lane & 7) * 8;   // bf16-element offset within row (16B/lane)

    const unsigned short* aptr[4];
    const unsigned short* bptr[4];
#pragma unroll
    for (int i = 0; i < 4; i++) {
        int c = wave * 4 + i;
        int ra = c * 8 + lr;                       // tile row 0..127
        int pos = m0 + ra;
        int cpos = pos < cnt ? pos : (cnt - 1);
        int entry = list[e * N_TOKENS + cpos];
        long arow = (LAYER == 1) ? (long)(entry >> 1) : (long)entry;
        aptr[i] = A_src + arow * KD + lc;
        long brow = (long)e * NO + n0 + ra;
        bptr[i] = B_src + brow * KD + lc;
    }

    f32x4 acc[4][4];
#pragma unroll
    for (int m = 0; m < 4; m++)
#pragma unroll
        for (int n = 0; n < 4; n++) acc[m][n] = f32x4{0.f, 0.f, 0.f, 0.f};

    const int wr = (wave >> 1) * 64, wc = (wave & 1) * 64;
    const int fr = lane & 15;        // fragment row (A) / out-col (B)
    const int fk = (lane >> 4) * 8;  // fragment k offset

    // prologue: stage tile 0 into buf 0
#pragma unroll
    for (int i = 0; i < 4; i++) {
        int c = wave * 4 + i;
        gload_lds16(aptr[i], &As[0][c * 8 * 64]);
        gload_lds16(bptr[i], &Bs[0][c * 8 * 64]);
    }
    __syncthreads();   // drains vmcnt(0): buf0 ready

    int buf = 0;
    for (int t = 0; t < NT; ++t) {
        // issue next tile's loads into the other buffer (overlap with compute below)
        if (t + 1 < NT) {
            int k0 = (t + 1) * 64;
#pragma unroll
            for (int i = 0; i < 4; i++) {
                int c = wave * 4 + i;
                gload_lds16(aptr[i] + k0, &As[buf ^ 1][c * 8 * 64]);
                gload_lds16(bptr[i] + k0, &Bs[buf ^ 1][c * 8 * 64]);
            }
        }
        // compute on current buffer
#pragma unroll
        for (int ks = 0; ks < 64; ks += 32) {
            bf16x8 af[4], bfr[4];
#pragma unroll
            for (int m = 0; m < 4; m++)
                af[m] = *reinterpret_cast<const bf16x8*>(&As[buf][(wr + m * 16 + fr) * 64 + ks + fk]);
#pragma unroll
            for (int n = 0; n < 4; n++)
                bfr[n] = *reinterpret_cast<const bf16x8*>(&Bs[buf][(wc + n * 16 + fr) * 64 + ks + fk]);
#pragma unroll
            for (int m = 0; m < 4; m++)
#pragma unroll
                for (int n = 0; n < 4; n++)
                    acc[m][n] = __builtin_amdgcn_mfma_f32_16x16x32_bf16(af[m], bfr[n], acc[m][n], 0, 0, 0);
        }
        __syncthreads();   // drains vmcnt(0) (next buf staged) + lgkmcnt; one barrier/iter
        buf ^= 1;
    }

    // epilogue: C/D layout col=lane&15, row=(lane>>4)*4+j  [m89/m91]
#pragma unroll
    for (int m = 0; m < 4; m++) {
#pragma unroll
        for (int j = 0; j < 4; j++) {
            int row = wr + m * 16 + ((lane >> 4) << 2) + j;
            int pos = m0 + row;
            if (pos >= cnt) continue;
            int entry = list[e * N_TOKENS + pos];
            if (LAYER == 1) {
                unsigned short* hrow = h_out + (long)entry * D_FF + n0;
#pragma unroll
                for (int n = 0; n < 4; n++) {
                    int col = wc + n * 16 + (lane & 15);
                    float v = acc[m][n][j] + bias[e * NO + n0 + col];
                    v = 0.5f * v * (1.f + erff(v * 0.70710678118654752440f));  // exact GELU
                    hrow[col] = f2bf(v);
                }
            } else {
                float w = pairw[e * N_TOKENS + pos];
                float* srow = slot_out + (long)entry * D_MODEL + n0;
#pragma unroll
                for (int n = 0; n < 4; n++) {
                    int col = wc + n * 16 + (lane & 15);
                    srow[col] = (acc[m][n][j] + bias[e * NO + n0 + col]) * w;  // plain store
                }
            }
        }
    }
}

// ---------------- combine: out[t] = slot[2t] + slot[2t+1] ----------------
__global__ __launch_bounds__(256) void combine_kernel(const float* __restrict__ slot,
                                                      float* __restrict__ out) {
    const long n4 = (long)N_TOKENS * D_MODEL / 4;
    const float4* s = reinterpret_cast<const float4*>(slot);
    float4* o = reinterpret_cast<float4*>(out);
    long i = (long)blockIdx.x * blockDim.x + threadIdx.x;
    long stride = (long)gridDim.x * blockDim.x;
    constexpr int C4 = D_MODEL / 4;  // 256
    for (; i < n4; i += stride) {
        long t = i >> 8;             // / 256
        long c = i & (C4 - 1);
        float4 a = s[(2 * t) * C4 + c];
        float4 b = s[(2 * t + 1) * C4 + c];
        float4 r; r.x = a.x + b.x; r.y = a.y + b.y; r.z = a.z + b.z; r.w = a.w + b.w;
        o[i] = r;
    }
}

extern "C" void kernel_launch(void* const* d_in, const int* in_sizes, int n_in,
                              void* d_out, int out_size, void* d_ws, size_t ws_size,
                              hipStream_t stream) {
    const float* x  = (const float*)d_in[0];
    const float* gw = (const float*)d_in[1];
    const float* w1 = (const float*)d_in[2];
    const float* b1 = (const float*)d_in[3];
    const float* w2 = (const float*)d_in[4];
    const float* b2 = (const float*)d_in[5];
    float* out = (float*)d_out;

    char* ws = (char*)d_ws;
    size_t off = 0;
    auto alloc = [&](size_t bytes) {
        void* p = ws + off;
        off += (bytes + 255) & ~(size_t)255;
        return p;
    };
    unsigned short* x_bf  = (unsigned short*)alloc(sizeof(unsigned short) * N_TOKENS * D_MODEL);
    unsigned short* w1_bf = (unsigned short*)alloc(sizeof(unsigned short) * N_EXPERTS * D_FF * D_MODEL);
    unsigned short* w2_bf = (unsigned short*)alloc(sizeof(unsigned short) * N_EXPERTS * D_MODEL * D_FF);
    unsigned short* h_bf  = (unsigned short*)alloc(sizeof(unsigned short) * (size_t)N_TOKENS * 2 * D_FF);
    int*   list  = (int*)alloc(sizeof(int) * N_EXPERTS * N_TOKENS);
    float* pairw = (float*)alloc(sizeof(float) * N_EXPERTS * N_TOKENS);
    int*   counts = (int*)alloc(sizeof(int) * N_EXPERTS);

    // slot buffer (16384 x 1024 f32 = 64 MB) aliases w1_bf (64 MB, dead after layer-1).
    // Same-stream ordering: cvt writes w1_bf -> gemm1 reads it -> gemm2 writes slot -> combine.
    float* slot = (float*)w1_bf;

    hipMemsetAsync(counts, 0, sizeof(int) * N_EXPERTS, stream);

    cvt_all<<<2048, 256, 0, stream>>>(
        x,  x_bf,  N_TOKENS * D_MODEL / 8,
        w1, w1_bf, N_EXPERTS * D_FF * D_MODEL / 8,
        w2, w2_bf, N_EXPERTS * D_MODEL * D_FF / 8);

    gate_kernel<<<N_TOKENS / 4, 256, 0, stream>>>(x, gw, counts, list, pairw);

    moe_gemm<1><<<(D_FF / 128) * 64 * N_EXPERTS, 256, 0, stream>>>(
        x_bf, w1_bf, b1, counts, list, pairw, h_bf, nullptr);
    moe_gemm<2><<<(D_MODEL / 128) * 64 * N_EXPERTS, 256, 0, stream>>>(
        h_bf, w2_bf, b2, counts, list, pairw, nullptr, slot);

    combine_kernel<<<2048, 256, 0, stream>>>(slot, out);
}

// Round 11
// 1159.152 us; speedup vs baseline: 1.2036x; 1.1640x over previous
//
#include <hip/hip_runtime.h>
#include <hip/hip_bf16.h>
#include <math.h>

// TokenMoE: x[4,2048,1024] fp32, 8 experts, top-2, D_FF=4096, exact-erf GELU.
// R9: STATIC double-buffer (compile-time LDS addressing; fixes R7's 4x VALU bloat),
//     panel-round-robin XCD remap, slot-store+combine. ws ~272 MB (slot aliases w1_bf).

#define D_MODEL 1024
#define N_EXPERTS 8
#define D_FF 4096
#define N_TOKENS 8192

typedef __attribute__((ext_vector_type(8))) short bf16x8;
typedef __attribute__((ext_vector_type(4))) float f32x4;
typedef __attribute__((ext_vector_type(8))) unsigned short ushort8;

__device__ inline unsigned short f2bf(float f) {
    unsigned int u = __float_as_uint(f);
    unsigned int r = (u + 0x7FFFu + ((u >> 16) & 1u)) >> 16;   // RNE
    return (unsigned short)r;
}

__device__ inline void gload_lds16(const void* g, void* l) {
    __builtin_amdgcn_global_load_lds(
        (const __attribute__((address_space(1))) unsigned int*)g,
        (__attribute__((address_space(3))) unsigned int*)l, 16, 0, 0);
}

// ---------------- fp32 -> bf16 conversion, 3 segments fused (8 elems/thread) -------------
__device__ inline void cvt8(const float* __restrict__ src, unsigned short* __restrict__ dst,
                            int i) {
    const float4* s = reinterpret_cast<const float4*>(src) + (size_t)i * 2;
    float4 a = s[0], b = s[1];
    ushort8 r;
    r[0] = f2bf(a.x); r[1] = f2bf(a.y); r[2] = f2bf(a.z); r[3] = f2bf(a.w);
    r[4] = f2bf(b.x); r[5] = f2bf(b.y); r[6] = f2bf(b.z); r[7] = f2bf(b.w);
    *reinterpret_cast<ushort8*>(dst + (size_t)i * 8) = r;
}

__global__ __launch_bounds__(256) void cvt_all(const float* __restrict__ s0, unsigned short* __restrict__ d0, int n0,
                                               const float* __restrict__ s1, unsigned short* __restrict__ d1, int n1,
                                               const float* __restrict__ s2, unsigned short* __restrict__ d2, int n2) {
    int i = blockIdx.x * blockDim.x + threadIdx.x;
    int stride = gridDim.x * blockDim.x;
    int total = n0 + n1 + n2;
    for (; i < total; i += stride) {
        if (i < n0)            cvt8(s0, d0, i);
        else if (i < n0 + n1)  cvt8(s1, d1, i - n0);
        else                   cvt8(s2, d2, i - n0 - n1);
    }
}

// ---------------- gating: logits, softmax, top-2, fill expert lists ----------------
__global__ __launch_bounds__(256) void gate_kernel(const float* __restrict__ x,
                                                   const float* __restrict__ gw,
                                                   int* __restrict__ counts,
                                                   int* __restrict__ list,
                                                   float* __restrict__ pairw) {
    int wave = threadIdx.x >> 6;
    int lane = threadIdx.x & 63;
    int t = blockIdx.x * 4 + wave;
    if (t >= N_TOKENS) return;

    const float4* xr = reinterpret_cast<const float4*>(x + (size_t)t * D_MODEL);
    float4 xv[4];
#pragma unroll
    for (int i = 0; i < 4; i++) xv[i] = xr[lane + 64 * i];

    float acc[N_EXPERTS];
#pragma unroll
    for (int e = 0; e < N_EXPERTS; e++) {
        const float4* gr = reinterpret_cast<const float4*>(gw + (size_t)e * D_MODEL);
        float s = 0.f;
#pragma unroll
        for (int i = 0; i < 4; i++) {
            float4 g = gr[lane + 64 * i];
            s += xv[i].x * g.x + xv[i].y * g.y + xv[i].z * g.z + xv[i].w * g.w;
        }
        acc[e] = s;
    }
#pragma unroll
    for (int e = 0; e < N_EXPERTS; e++) {
        float s = acc[e];
#pragma unroll
        for (int off = 32; off; off >>= 1) s += __shfl_xor(s, off, 64);
        acc[e] = s;
    }
    if (lane == 0) {
        float m = acc[0];
#pragma unroll
        for (int e = 1; e < N_EXPERTS; e++) m = fmaxf(m, acc[e]);
        float p[N_EXPERTS], sum = 0.f;
#pragma unroll
        for (int e = 0; e < N_EXPERTS; e++) { p[e] = expf(acc[e] - m); sum += p[e]; }
        float inv = 1.f / sum;
#pragma unroll
        for (int e = 0; e < N_EXPERTS; e++) p[e] *= inv;
        int i1 = 0;
#pragma unroll
        for (int e = 1; e < N_EXPERTS; e++) if (p[e] > p[i1]) i1 = e;
        int i2 = (i1 == 0) ? 1 : 0;
#pragma unroll
        for (int e = 0; e < N_EXPERTS; e++) {
            if (e == i1) continue;
            if (p[e] > p[i2]) i2 = e;
        }
        int pos1 = atomicAdd(&counts[i1], 1);
        list[i1 * N_TOKENS + pos1] = t * 2 + 0;
        pairw[i1 * N_TOKENS + pos1] = p[i1];
        int pos2 = atomicAdd(&counts[i2], 1);
        list[i2 * N_TOKENS + pos2] = t * 2 + 1;
        pairw[i2 * N_TOKENS + pos2] = p[i2];
    }
}

// ---------------- grouped GEMM: 128x128 tile, BK=64, 4 waves, STATIC dbuf prefetch -------
// LAYER==1: h[entry] = gelu(x[t] @ w1[e]^T + b1[e])
// LAYER==2: slot[entry] = pairw * (h[entry] @ w2[e]^T + b2[e])   (plain stores)
template <int LAYER>
__global__ __launch_bounds__(256) void moe_gemm(const unsigned short* __restrict__ A_src,
                                                const unsigned short* __restrict__ B_src,
                                                const float* __restrict__ bias,
                                                const int* __restrict__ counts,
                                                const int* __restrict__ list,
                                                const float* __restrict__ pairw,
                                                unsigned short* __restrict__ h_out,
                                                float* __restrict__ slot_out) {
    constexpr int KD = (LAYER == 1) ? D_MODEL : D_FF;   // reduction dim
    constexpr int NO = (LAYER == 1) ? D_FF : D_MODEL;   // output cols
    constexpr int NBLK = NO / 128;                      // 32 or 8 (pow2)
    constexpr int NBSH = (NBLK == 32) ? 5 : 3;
    constexpr int MBLK = 64;                            // covers worst-case cnt=8192
    constexpr int NT = KD / 64;                         // 16 or 64 (even)

    // Panel-round-robin XCD remap: panel p=(e,nb), p%8 == xcd (balanced: each XCD
    // gets NBLK/8 panels of EVERY expert); mb runs contiguously on one XCD so the
    // 128-col B-panel slice stays hot in that XCD's L2.
    long bid = blockIdx.x;
    const int xcd = (int)(bid & 7);
    long seq = bid >> 3;                       // [0, P*MBLK/8)
    const int mb = (int)(seq & (MBLK - 1));    // fastest: same panel for 64 consecutive seq
    const int p  = (int)((seq >> 6) * 8 + xcd);
    const int e  = p >> NBSH;
    const int nb = p & (NBLK - 1);

    const int cnt = counts[e];
    const int m0 = mb * 128;
    if (m0 >= cnt) return;
    const int n0 = nb * 128;

    // STATIC double buffers: all LDS addresses compile-time (R7's runtime As[buf]
    // indexing quadrupled VALU-busy; this is the fix).
    __shared__ __align__(16) unsigned short As0[128 * 64];
    __shared__ __align__(16) unsigned short Bs0[128 * 64];
    __shared__ __align__(16) unsigned short As1[128 * 64];
    __shared__ __align__(16) unsigned short Bs1[128 * 64];

    const int tid = threadIdx.x;
    const int wave = tid >> 6, lane = tid & 63;
    const int lr = lane >> 3;        // row within 8-row staging chunk
    const int lc = (lane & 7) * 8;   // bf16-element offset within row (16B/lane)

    const unsigned short* aptr[4];
    const unsigned short* bptr[4];
#pragma unroll
    for (int i = 0; i < 4; i++) {
        int c = wave * 4 + i;
        int ra = c * 8 + lr;                       // tile row 0..127
        int pos = m0 + ra;
        int cpos = pos < cnt ? pos : (cnt - 1);
        int entry = list[e * N_TOKENS + cpos];
        long arow = (LAYER == 1) ? (long)(entry >> 1) : (long)entry;
        aptr[i] = A_src + arow * KD + lc;
        long brow = (long)e * NO + n0 + ra;
        bptr[i] = B_src + brow * KD + lc;
    }

    f32x4 acc[4][4];
#pragma unroll
    for (int m = 0; m < 4; m++)
#pragma unroll
        for (int n = 0; n < 4; n++) acc[m][n] = f32x4{0.f, 0.f, 0.f, 0.f};

    const int wr = (wave >> 1) * 64, wc = (wave & 1) * 64;
    const int fr = lane & 15;        // fragment row (A) / out-col (B)
    const int fk = (lane >> 4) * 8;  // fragment k offset

    auto STAGE = [&](unsigned short* As_, unsigned short* Bs_, int k0) {
#pragma unroll
        for (int i = 0; i < 4; i++) {
            int c = wave * 4 + i;
            gload_lds16(aptr[i] + k0, As_ + c * 8 * 64);
            gload_lds16(bptr[i] + k0, Bs_ + c * 8 * 64);
        }
    };
    auto COMPUTE = [&](const unsigned short* As_, const unsigned short* Bs_) {
#pragma unroll
        for (int ks = 0; ks < 64; ks += 32) {
            bf16x8 af[4], bfr[4];
#pragma unroll
            for (int m = 0; m < 4; m++)
                af[m] = *reinterpret_cast<const bf16x8*>(&As_[(wr + m * 16 + fr) * 64 + ks + fk]);
#pragma unroll
            for (int n = 0; n < 4; n++)
                bfr[n] = *reinterpret_cast<const bf16x8*>(&Bs_[(wc + n * 16 + fr) * 64 + ks + fk]);
#pragma unroll
            for (int m = 0; m < 4; m++)
#pragma unroll
                for (int n = 0; n < 4; n++)
                    acc[m][n] = __builtin_amdgcn_mfma_f32_16x16x32_bf16(af[m], bfr[n], acc[m][n], 0, 0, 0);
        }
    };

    // prologue: stage tile 0 into buf0
    STAGE(As0, Bs0, 0);
    __syncthreads();   // vmcnt(0) drained: buf0 ready

    // 2-step unrolled double-buffer loop, NT even.
    // Barrier protects: (a) staged buffer complete (vmcnt drain), (b) all waves
    // done reading the buffer about to be overwritten.
#pragma unroll 1
    for (int t = 0; t < NT; t += 2) {
        STAGE(As1, Bs1, (t + 1) * 64);           // issue; latency hidden under COMPUTE
        COMPUTE(As0, Bs0);
        __syncthreads();
        if (t + 2 < NT) STAGE(As0, Bs0, (t + 2) * 64);
        COMPUTE(As1, Bs1);
        __syncthreads();
    }

    // epilogue: C/D layout col=lane&15, row=(lane>>4)*4+j  [m89/m91]
#pragma unroll
    for (int m = 0; m < 4; m++) {
#pragma unroll
        for (int j = 0; j < 4; j++) {
            int row = wr + m * 16 + ((lane >> 4) << 2) + j;
            int pos = m0 + row;
            if (pos >= cnt) continue;
            int entry = list[e * N_TOKENS + pos];
            if (LAYER == 1) {
                unsigned short* hrow = h_out + (long)entry * D_FF + n0;
#pragma unroll
                for (int n = 0; n < 4; n++) {
                    int col = wc + n * 16 + (lane & 15);
                    float v = acc[m][n][j] + bias[e * NO + n0 + col];
                    v = 0.5f * v * (1.f + erff(v * 0.70710678118654752440f));  // exact GELU
                    hrow[col] = f2bf(v);
                }
            } else {
                float w = pairw[e * N_TOKENS + pos];
                float* srow = slot_out + (long)entry * D_MODEL + n0;
#pragma unroll
                for (int n = 0; n < 4; n++) {
                    int col = wc + n * 16 + (lane & 15);
                    srow[col] = (acc[m][n][j] + bias[e * NO + n0 + col]) * w;  // plain store
                }
            }
        }
    }
}

// ---------------- combine: out[t] = slot[2t] + slot[2t+1] ----------------
__global__ __launch_bounds__(256) void combine_kernel(const float* __restrict__ slot,
                                                      float* __restrict__ out) {
    const long n4 = (long)N_TOKENS * D_MODEL / 4;
    const float4* s = reinterpret_cast<const float4*>(slot);
    float4* o = reinterpret_cast<float4*>(out);
    long i = (long)blockIdx.x * blockDim.x + threadIdx.x;
    long stride = (long)gridDim.x * blockDim.x;
    constexpr int C4 = D_MODEL / 4;  // 256
    for (; i < n4; i += stride) {
        long t = i >> 8;             // / 256
        long c = i & (C4 - 1);
        float4 a = s[(2 * t) * C4 + c];
        float4 b = s[(2 * t + 1) * C4 + c];
        float4 r; r.x = a.x + b.x; r.y = a.y + b.y; r.z = a.z + b.z; r.w = a.w + b.w;
        o[i] = r;
    }
}

extern "C" void kernel_launch(void* const* d_in, const int* in_sizes, int n_in,
                              void* d_out, int out_size, void* d_ws, size_t ws_size,
                              hipStream_t stream) {
    const float* x  = (const float*)d_in[0];
    const float* gw = (const float*)d_in[1];
    const float* w1 = (const float*)d_in[2];
    const float* b1 = (const float*)d_in[3];
    const float* w2 = (const float*)d_in[4];
    const float* b2 = (const float*)d_in[5];
    float* out = (float*)d_out;

    char* ws = (char*)d_ws;
    size_t off = 0;
    auto alloc = [&](size_t bytes) {
        void* p = ws + off;
        off += (bytes + 255) & ~(size_t)255;
        return p;
    };
    unsigned short* x_bf  = (unsigned short*)alloc(sizeof(unsigned short) * N_TOKENS * D_MODEL);
    unsigned short* w1_bf = (unsigned short*)alloc(sizeof(unsigned short) * N_EXPERTS * D_FF * D_MODEL);
    unsigned short* w2_bf = (unsigned short*)alloc(sizeof(unsigned short) * N_EXPERTS * D_MODEL * D_FF);
    unsigned short* h_bf  = (unsigned short*)alloc(sizeof(unsigned short) * (size_t)N_TOKENS * 2 * D_FF);
    int*   list  = (int*)alloc(sizeof(int) * N_EXPERTS * N_TOKENS);
    float* pairw = (float*)alloc(sizeof(float) * N_EXPERTS * N_TOKENS);
    int*   counts = (int*)alloc(sizeof(int) * N_EXPERTS);

    // slot buffer (16384 x 1024 f32 = 64 MB) aliases w1_bf (64 MB, dead after layer-1).
    // Same-stream ordering: cvt writes w1_bf -> gemm1 reads it -> gemm2 writes slot -> combine.
    float* slot = (float*)w1_bf;

    hipMemsetAsync(counts, 0, sizeof(int) * N_EXPERTS, stream);

    cvt_all<<<2048, 256, 0, stream>>>(
        x,  x_bf,  N_TOKENS * D_MODEL / 8,
        w1, w1_bf, N_EXPERTS * D_FF * D_MODEL / 8,
        w2, w2_bf, N_EXPERTS * D_MODEL * D_FF / 8);

    gate_kernel<<<N_TOKENS / 4, 256, 0, stream>>>(x, gw, counts, list, pairw);

    moe_gemm<1><<<(D_FF / 128) * 64 * N_EXPERTS, 256, 0, stream>>>(
        x_bf, w1_bf, b1, counts, list, pairw, h_bf, nullptr);
    moe_gemm<2><<<(D_MODEL / 128) * 64 * N_EXPERTS, 256, 0, stream>>>(
        h_bf, w2_bf, b2, counts, list, pairw, nullptr, slot);

    combine_kernel<<<2048, 256, 0, stream>>>(slot, out);
}

// Round 12
// 1048.008 us; speedup vs baseline: 1.3312x; 1.1061x over previous
//
#include <hip/hip_runtime.h>
#include <hip/hip_bf16.h>
#include <math.h>

// TokenMoE: x[4,2048,1024] fp32, 8 experts, top-2, D_FF=4096, exact-erf GELU.
// R12: + T2 XOR-swizzle (pre-swizzled global source + swizzled ds_read; kills the
//      16-way LDS bank conflict, 5.19e7 cyc) and fast-poly erf (cuts L1 epilogue VALU).
//      Static dbuf, panel-RR XCD remap, slot-store+combine. ws ~272 MB.

#define D_MODEL 1024
#define N_EXPERTS 8
#define D_FF 4096
#define N_TOKENS 8192

typedef __attribute__((ext_vector_type(8))) short bf16x8;
typedef __attribute__((ext_vector_type(4))) float f32x4;
typedef __attribute__((ext_vector_type(8))) unsigned short ushort8;

__device__ inline unsigned short f2bf(float f) {
    unsigned int u = __float_as_uint(f);
    unsigned int r = (u + 0x7FFFu + ((u >> 16) & 1u)) >> 16;   // RNE
    return (unsigned short)r;
}

__device__ inline void gload_lds16(const void* g, void* l) {
    __builtin_amdgcn_global_load_lds(
        (const __attribute__((address_space(1))) unsigned int*)g,
        (__attribute__((address_space(3))) unsigned int*)l, 16, 0, 0);
}

// GELU with Abramowitz-Stegun 7.1.26 erf (|err| <= 1.5e-7; bf16 rounding dominates).
// ~15 VALU ops vs libm erff's ~60+.
__device__ inline float gelu_fast(float v) {
    float x = v * 0.70710678118654752440f;
    float ax = fabsf(x);
    float t = __builtin_amdgcn_rcpf(1.0f + 0.3275911f * ax);
    float y = t * (0.254829592f + t * (-0.284496736f + t * (1.421413741f +
              t * (-1.453152027f + t * 1.061405429f))));
    float e = __expf(-x * x);
    float erfv = 1.0f - y * e;
    erfv = copysignf(erfv, x);
    return 0.5f * v * (1.0f + erfv);
}

// ---------------- fp32 -> bf16 conversion, 3 segments fused (8 elems/thread) -------------
__device__ inline void cvt8(const float* __restrict__ src, unsigned short* __restrict__ dst,
                            int i) {
    const float4* s = reinterpret_cast<const float4*>(src) + (size_t)i * 2;
    float4 a = s[0], b = s[1];
    ushort8 r;
    r[0] = f2bf(a.x); r[1] = f2bf(a.y); r[2] = f2bf(a.z); r[3] = f2bf(a.w);
    r[4] = f2bf(b.x); r[5] = f2bf(b.y); r[6] = f2bf(b.z); r[7] = f2bf(b.w);
    *reinterpret_cast<ushort8*>(dst + (size_t)i * 8) = r;
}

__global__ __launch_bounds__(256) void cvt_all(const float* __restrict__ s0, unsigned short* __restrict__ d0, int n0,
                                               const float* __restrict__ s1, unsigned short* __restrict__ d1, int n1,
                                               const float* __restrict__ s2, unsigned short* __restrict__ d2, int n2) {
    int i = blockIdx.x * blockDim.x + threadIdx.x;
    int stride = gridDim.x * blockDim.x;
    int total = n0 + n1 + n2;
    for (; i < total; i += stride) {
        if (i < n0)            cvt8(s0, d0, i);
        else if (i < n0 + n1)  cvt8(s1, d1, i - n0);
        else                   cvt8(s2, d2, i - n0 - n1);
    }
}

// ---------------- gating: logits, softmax, top-2, fill expert lists ----------------
__global__ __launch_bounds__(256) void gate_kernel(const float* __restrict__ x,
                                                   const float* __restrict__ gw,
                                                   int* __restrict__ counts,
                                                   int* __restrict__ list,
                                                   float* __restrict__ pairw) {
    int wave = threadIdx.x >> 6;
    int lane = threadIdx.x & 63;
    int t = blockIdx.x * 4 + wave;
    if (t >= N_TOKENS) return;

    const float4* xr = reinterpret_cast<const float4*>(x + (size_t)t * D_MODEL);
    float4 xv[4];
#pragma unroll
    for (int i = 0; i < 4; i++) xv[i] = xr[lane + 64 * i];

    float acc[N_EXPERTS];
#pragma unroll
    for (int e = 0; e < N_EXPERTS; e++) {
        const float4* gr = reinterpret_cast<const float4*>(gw + (size_t)e * D_MODEL);
        float s = 0.f;
#pragma unroll
        for (int i = 0; i < 4; i++) {
            float4 g = gr[lane + 64 * i];
            s += xv[i].x * g.x + xv[i].y * g.y + xv[i].z * g.z + xv[i].w * g.w;
        }
        acc[e] = s;
    }
#pragma unroll
    for (int e = 0; e < N_EXPERTS; e++) {
        float s = acc[e];
#pragma unroll
        for (int off = 32; off; off >>= 1) s += __shfl_xor(s, off, 64);
        acc[e] = s;
    }
    if (lane == 0) {
        float m = acc[0];
#pragma unroll
        for (int e = 1; e < N_EXPERTS; e++) m = fmaxf(m, acc[e]);
        float p[N_EXPERTS], sum = 0.f;
#pragma unroll
        for (int e = 0; e < N_EXPERTS; e++) { p[e] = expf(acc[e] - m); sum += p[e]; }
        float inv = 1.f / sum;
#pragma unroll
        for (int e = 0; e < N_EXPERTS; e++) p[e] *= inv;
        int i1 = 0;
#pragma unroll
        for (int e = 1; e < N_EXPERTS; e++) if (p[e] > p[i1]) i1 = e;
        int i2 = (i1 == 0) ? 1 : 0;
#pragma unroll
        for (int e = 0; e < N_EXPERTS; e++) {
            if (e == i1) continue;
            if (p[e] > p[i2]) i2 = e;
        }
        int pos1 = atomicAdd(&counts[i1], 1);
        list[i1 * N_TOKENS + pos1] = t * 2 + 0;
        pairw[i1 * N_TOKENS + pos1] = p[i1];
        int pos2 = atomicAdd(&counts[i2], 1);
        list[i2 * N_TOKENS + pos2] = t * 2 + 1;
        pairw[i2 * N_TOKENS + pos2] = p[i2];
    }
}

// ---------------- grouped GEMM: 128x128 tile, BK=64, static dbuf, XOR-swizzled LDS -------
// Swizzle (rule #21, both sides): LDS[row][slot s] holds G[row][k0 + (s^(row&7))*8].
//   write side: gload_lds writes linearly; lane's GLOBAL col pre-swizzled
//               (lc = ((lane&7)^(lane>>3))*8, since staged row&7 == lane>>3).
//   read side:  slot = ((ks>>3)+(lane>>4)) ^ (lane&7)   (row&7 == lane&7 for all frags).
// Result: ds_read_b128 16-way bank conflict -> 2-way (free).
// LAYER==1: h[entry] = gelu(x[t] @ w1[e]^T + b1[e])
// LAYER==2: slot[entry] = pairw * (h[entry] @ w2[e]^T + b2[e])   (plain stores)
template <int LAYER>
__global__ __launch_bounds__(256) void moe_gemm(const unsigned short* __restrict__ A_src,
                                                const unsigned short* __restrict__ B_src,
                                                const float* __restrict__ bias,
                                                const int* __restrict__ counts,
                                                const int* __restrict__ list,
                                                const float* __restrict__ pairw,
                                                unsigned short* __restrict__ h_out,
                                                float* __restrict__ slot_out) {
    constexpr int KD = (LAYER == 1) ? D_MODEL : D_FF;   // reduction dim
    constexpr int NO = (LAYER == 1) ? D_FF : D_MODEL;   // output cols
    constexpr int NBLK = NO / 128;                      // 32 or 8 (pow2)
    constexpr int NBSH = (NBLK == 32) ? 5 : 3;
    constexpr int MBLK = 64;                            // covers worst-case cnt=8192
    constexpr int NT = KD / 64;                         // 16 or 64 (even)

    // Panel-round-robin XCD remap (balanced per expert, L2 panel reuse).
    long bid = blockIdx.x;
    const int xcd = (int)(bid & 7);
    long seq = bid >> 3;
    const int mb = (int)(seq & (MBLK - 1));
    const int p  = (int)((seq >> 6) * 8 + xcd);
    const int e  = p >> NBSH;
    const int nb = p & (NBLK - 1);

    const int cnt = counts[e];
    const int m0 = mb * 128;
    if (m0 >= cnt) return;
    const int n0 = nb * 128;

    // Static double buffers (compile-time LDS addressing).
    __shared__ __align__(16) unsigned short As0[128 * 64];
    __shared__ __align__(16) unsigned short Bs0[128 * 64];
    __shared__ __align__(16) unsigned short As1[128 * 64];
    __shared__ __align__(16) unsigned short Bs1[128 * 64];

    const int tid = threadIdx.x;
    const int wave = tid >> 6, lane = tid & 63;
    const int lr = lane >> 3;                        // staged row within 8-row chunk = row&7
    const int lc = ((lane & 7) ^ lr) * 8;            // PRE-SWIZZLED global col (bf16 elems)

    const unsigned short* aptr[4];
    const unsigned short* bptr[4];
#pragma unroll
    for (int i = 0; i < 4; i++) {
        int c = wave * 4 + i;
        int ra = c * 8 + lr;                       // tile row 0..127
        int pos = m0 + ra;
        int cpos = pos < cnt ? pos : (cnt - 1);
        int entry = list[e * N_TOKENS + cpos];
        long arow = (LAYER == 1) ? (long)(entry >> 1) : (long)entry;
        aptr[i] = A_src + arow * KD + lc;
        long brow = (long)e * NO + n0 + ra;
        bptr[i] = B_src + brow * KD + lc;
    }

    f32x4 acc[4][4];
#pragma unroll
    for (int m = 0; m < 4; m++)
#pragma unroll
        for (int n = 0; n < 4; n++) acc[m][n] = f32x4{0.f, 0.f, 0.f, 0.f};

    const int wr = (wave >> 1) * 64, wc = (wave & 1) * 64;
    const int fr = lane & 15;        // fragment row (A) / out-col (B)

    auto STAGE = [&](unsigned short* As_, unsigned short* Bs_, int k0) {
#pragma unroll
        for (int i = 0; i < 4; i++) {
            int c = wave * 4 + i;
            gload_lds16(aptr[i] + k0, As_ + c * 8 * 64);
            gload_lds16(bptr[i] + k0, Bs_ + c * 8 * 64);
        }
    };
    auto COMPUTE = [&](const unsigned short* As_, const unsigned short* Bs_) {
#pragma unroll
        for (int ks = 0; ks < 64; ks += 32) {
            // swizzled k-slot: slot_orig = ks/8 + lane>>4, XOR row&7 (== lane&7)
            const int sl = ((((ks >> 3) + (lane >> 4)) ^ (lane & 7)) * 8);
            bf16x8 af[4], bfr[4];
#pragma unroll
            for (int m = 0; m < 4; m++)
                af[m] = *reinterpret_cast<const bf16x8*>(&As_[(wr + m * 16 + fr) * 64 + sl]);
#pragma unroll
            for (int n = 0; n < 4; n++)
                bfr[n] = *reinterpret_cast<const bf16x8*>(&Bs_[(wc + n * 16 + fr) * 64 + sl]);
#pragma unroll
            for (int m = 0; m < 4; m++)
#pragma unroll
                for (int n = 0; n < 4; n++)
                    acc[m][n] = __builtin_amdgcn_mfma_f32_16x16x32_bf16(af[m], bfr[n], acc[m][n], 0, 0, 0);
        }
    };

    // prologue: stage tile 0 into buf0
    STAGE(As0, Bs0, 0);
    __syncthreads();   // vmcnt(0) drained: buf0 ready

#pragma unroll 1
    for (int t = 0; t < NT; t += 2) {
        STAGE(As1, Bs1, (t + 1) * 64);           // issue; latency hidden under COMPUTE
        COMPUTE(As0, Bs0);
        __syncthreads();
        if (t + 2 < NT) STAGE(As0, Bs0, (t + 2) * 64);
        COMPUTE(As1, Bs1);
        __syncthreads();
    }

    // epilogue: C/D layout col=lane&15, row=(lane>>4)*4+j  [m89/m91]
#pragma unroll
    for (int m = 0; m < 4; m++) {
#pragma unroll
        for (int j = 0; j < 4; j++) {
            int row = wr + m * 16 + ((lane >> 4) << 2) + j;
            int pos = m0 + row;
            if (pos >= cnt) continue;
            int entry = list[e * N_TOKENS + pos];
            if (LAYER == 1) {
                unsigned short* hrow = h_out + (long)entry * D_FF + n0;
#pragma unroll
                for (int n = 0; n < 4; n++) {
                    int col = wc + n * 16 + (lane & 15);
                    float v = acc[m][n][j] + bias[e * NO + n0 + col];
                    hrow[col] = f2bf(gelu_fast(v));
                }
            } else {
                float w = pairw[e * N_TOKENS + pos];
                float* srow = slot_out + (long)entry * D_MODEL + n0;
#pragma unroll
                for (int n = 0; n < 4; n++) {
                    int col = wc + n * 16 + (lane & 15);
                    srow[col] = (acc[m][n][j] + bias[e * NO + n0 + col]) * w;  // plain store
                }
            }
        }
    }
}

// ---------------- combine: out[t] = slot[2t] + slot[2t+1] ----------------
__global__ __launch_bounds__(256) void combine_kernel(const float* __restrict__ slot,
                                                      float* __restrict__ out) {
    const long n4 = (long)N_TOKENS * D_MODEL / 4;
    const float4* s = reinterpret_cast<const float4*>(slot);
    float4* o = reinterpret_cast<float4*>(out);
    long i = (long)blockIdx.x * blockDim.x + threadIdx.x;
    long stride = (long)gridDim.x * blockDim.x;
    constexpr int C4 = D_MODEL / 4;  // 256
    for (; i < n4; i += stride) {
        long t = i >> 8;             // / 256
        long c = i & (C4 - 1);
        float4 a = s[(2 * t) * C4 + c];
        float4 b = s[(2 * t + 1) * C4 + c];
        float4 r; r.x = a.x + b.x; r.y = a.y + b.y; r.z = a.z + b.z; r.w = a.w + b.w;
        o[i] = r;
    }
}

extern "C" void kernel_launch(void* const* d_in, const int* in_sizes, int n_in,
                              void* d_out, int out_size, void* d_ws, size_t ws_size,
                              hipStream_t stream) {
    const float* x  = (const float*)d_in[0];
    const float* gw = (const float*)d_in[1];
    const float* w1 = (const float*)d_in[2];
    const float* b1 = (const float*)d_in[3];
    const float* w2 = (const float*)d_in[4];
    const float* b2 = (const float*)d_in[5];
    float* out = (float*)d_out;

    char* ws = (char*)d_ws;
    size_t off = 0;
    auto alloc = [&](size_t bytes) {
        void* p = ws + off;
        off += (bytes + 255) & ~(size_t)255;
        return p;
    };
    unsigned short* x_bf  = (unsigned short*)alloc(sizeof(unsigned short) * N_TOKENS * D_MODEL);
    unsigned short* w1_bf = (unsigned short*)alloc(sizeof(unsigned short) * N_EXPERTS * D_FF * D_MODEL);
    unsigned short* w2_bf = (unsigned short*)alloc(sizeof(unsigned short) * N_EXPERTS * D_MODEL * D_FF);
    unsigned short* h_bf  = (unsigned short*)alloc(sizeof(unsigned short) * (size_t)N_TOKENS * 2 * D_FF);
    int*   list  = (int*)alloc(sizeof(int) * N_EXPERTS * N_TOKENS);
    float* pairw = (float*)alloc(sizeof(float) * N_EXPERTS * N_TOKENS);
    int*   counts = (int*)alloc(sizeof(int) * N_EXPERTS);

    // slot buffer (16384 x 1024 f32 = 64 MB) aliases w1_bf (64 MB, dead after layer-1).
    float* slot = (float*)w1_bf;

    hipMemsetAsync(counts, 0, sizeof(int) * N_EXPERTS, stream);

    cvt_all<<<2048, 256, 0, stream>>>(
        x,  x_bf,  N_TOKENS * D_MODEL / 8,
        w1, w1_bf, N_EXPERTS * D_FF * D_MODEL / 8,
        w2, w2_bf, N_EXPERTS * D_MODEL * D_FF / 8);

    gate_kernel<<<N_TOKENS / 4, 256, 0, stream>>>(x, gw, counts, list, pairw);

    moe_gemm<1><<<(D_FF / 128) * 64 * N_EXPERTS, 256, 0, stream>>>(
        x_bf, w1_bf, b1, counts, list, pairw, h_bf, nullptr);
    moe_gemm<2><<<(D_MODEL / 128) * 64 * N_EXPERTS, 256, 0, stream>>>(
        h_bf, w2_bf, b2, counts, list, pairw, nullptr, slot);

    combine_kernel<<<2048, 256, 0, stream>>>(slot, out);
}